// Round 1
// baseline (137.259 us; speedup 1.0000x reference)
//
#include <hip/hip_runtime.h>

// CARAFE upsample: B=2, C=256, H=W=64, S=2, K=5, COMP=64, KP=100
// Stages: encoder (1x1 conv) -> kp conv (3x3) -> shuffle+softmax -> gather.

#define NB 2
#define NC 256
#define NH 64
#define NW 64
#define NCOMP 64
#define NK2 25

// ---------------- W reorder: wr[g][ch][co][d][k2] ----------------
__global__ __launch_bounds__(256) void reorder_wkp(const float* __restrict__ w_kp,
                                                   float* __restrict__ wr) {
    int idx = blockIdx.x * 256 + threadIdx.x;
    if (idx >= 4 * 2 * 32 * 9 * 25) return;
    int k2 = idx % 25;
    int d  = (idx / 25) % 9;
    int co = (idx / 225) % 32;
    int ch = (idx / 7200) % 2;
    int g  = idx / 14400;
    int kp = k2 * 4 + g;          // channel = k2*4 + p*2 + q, g = p*2+q
    int cog = ch * 32 + co;
    wr[idx] = w_kp[(kp * 64 + cog) * 9 + d];
}

// ---------------- A: encoder, xc[b][o][h][w] ----------------
// grid 256: bid -> (b, h, co-half); 256 thr: w=tid&63, og=tid>>6 (8 outputs each)
__global__ __launch_bounds__(256) void encoder_kernel(const float* __restrict__ x,
        const float* __restrict__ w_enc, const float* __restrict__ b_enc,
        float* __restrict__ xc) {
    __shared__ float xs[256 * 64];   // 64 KB: x[b][:][h][:]
    int bid = blockIdx.x;
    int half = bid & 1;
    int h = (bid >> 1) & 63;
    int b = bid >> 7;
    for (int i = 0; i < 64; ++i) {
        int f = i * 256 + threadIdx.x;
        int c = f >> 6, w = f & 63;
        xs[f] = x[((size_t)(b * NC + c)) * 4096 + h * 64 + w];
    }
    __syncthreads();
    int wl = threadIdx.x & 63;
    int og = threadIdx.x >> 6;
    int o0 = half * 32 + og * 8;
    float acc[8];
#pragma unroll
    for (int k = 0; k < 8; ++k) acc[k] = 0.f;
    for (int c = 0; c < 256; ++c) {
        float xv = xs[c * 64 + wl];
#pragma unroll
        for (int k = 0; k < 8; ++k)
            acc[k] = fmaf(xv, w_enc[(o0 + k) * 256 + c], acc[k]);
    }
#pragma unroll
    for (int k = 0; k < 8; ++k)
        xc[((size_t)(b * NCOMP + o0 + k)) * 4096 + h * 64 + wl] = acc[k] + b_enc[o0 + k];
}

// ---------------- B1: 3x3 conv partials (co-split x2) ----------------
// grid 256: bid = ((b*8+ty)*8+tx)*2+ch ; 256 thr: lane=pixel(8x8), wave=g
// plog[ch][b][g][k2][tile*64+lane]
__global__ __launch_bounds__(256) void kp_conv_kernel(const float* __restrict__ xc,
        const float* __restrict__ wr, float* __restrict__ plog) {
    __shared__ float xcs[32 * 100];   // [co][10*10] halo tile
    int bid = blockIdx.x;
    int ch = bid & 1;
    int tx = (bid >> 1) & 7;
    int ty = (bid >> 4) & 7;
    int b  = bid >> 7;
    for (int i = 0; i < 13; ++i) {
        int f = i * 256 + threadIdx.x;
        if (f < 3200) {
            int co = f / 100, pos = f % 100;
            int r = pos / 10, s = pos % 10;
            int hh = ty * 8 + r - 1, ww = tx * 8 + s - 1;
            float v = 0.f;
            if (hh >= 0 && hh < 64 && ww >= 0 && ww < 64)
                v = xc[((size_t)(b * NCOMP + ch * 32 + co)) * 4096 + hh * 64 + ww];
            xcs[f] = v;
        }
    }
    __syncthreads();
    int lane = threadIdx.x & 63;
    int g = threadIdx.x >> 6;     // wave-uniform subpixel
    int hy = lane >> 3, hx = lane & 7;
    int base = hy * 10 + hx;
    const float* wrg = wr + ((size_t)(g * 2 + ch)) * 32 * 225;
    float acc[25];
#pragma unroll
    for (int k = 0; k < 25; ++k) acc[k] = 0.f;
    for (int co = 0; co < 32; ++co) {
        const float* wp = wrg + co * 225;
        const float* xp = xcs + co * 100 + base;
#pragma unroll
        for (int di = 0; di < 3; ++di)
#pragma unroll
            for (int dj = 0; dj < 3; ++dj) {
                float xv = xp[di * 10 + dj];
                const float* w25 = wp + (di * 3 + dj) * 25;
#pragma unroll
                for (int k = 0; k < 25; ++k)
                    acc[k] = fmaf(xv, w25[k], acc[k]);
            }
    }
    int tile = ty * 8 + tx;
    size_t o0 = (((size_t)(ch * 2 + b) * 4 + g) * 25) * 4096 + tile * 64 + lane;
#pragma unroll
    for (int k = 0; k < 25; ++k) plog[o0 + (size_t)k * 4096] = acc[k];
}

// ---------------- B2: combine + bias + softmax; ker3[b][tile][g][k2][lane] ----------------
__global__ __launch_bounds__(256) void softmax_kernel(const float* __restrict__ plog,
        const float* __restrict__ b_kp, float* __restrict__ ker3) {
    int bid = blockIdx.x;           // 128: (b, tile)
    int tile = bid & 63;
    int b = bid >> 6;
    int lane = threadIdx.x & 63;
    int g = threadIdx.x >> 6;
    size_t i0 = (((size_t)(0 * 2 + b) * 4 + g) * 25) * 4096 + tile * 64 + lane;
    size_t i1 = (((size_t)(1 * 2 + b) * 4 + g) * 25) * 4096 + tile * 64 + lane;
    float l[25];
#pragma unroll
    for (int k = 0; k < 25; ++k)
        l[k] = plog[i0 + (size_t)k * 4096] + plog[i1 + (size_t)k * 4096] + b_kp[k * 4 + g];
    float m = l[0];
#pragma unroll
    for (int k = 1; k < 25; ++k) m = fmaxf(m, l[k]);
    float s = 0.f;
#pragma unroll
    for (int k = 0; k < 25; ++k) { l[k] = __expf(l[k] - m); s += l[k]; }
    float inv = 1.f / s;
    size_t o0 = (((size_t)(b * 64 + tile) * 4 + g) * 25) * 64 + lane;
#pragma unroll
    for (int k = 0; k < 25; ++k) ker3[o0 + (size_t)k * 64] = l[k] * inv;
}

// ---------------- C: gather ----------------
// grid 512: bid -> (b, tile, cblk64); 256 thr = 4 waves (16 ch each), lane = low-res pixel
__global__ __launch_bounds__(256) void gather_kernel(const float* __restrict__ x,
        const float* __restrict__ ker3, float* __restrict__ out) {
    __shared__ float xs[64 * 144];   // [ch][12][12], 36.9 KB
    int bid = blockIdx.x;
    int cblk = bid & 3;
    int tile = (bid >> 2) & 63;
    int b = bid >> 8;
    int ty = tile >> 3, tx = tile & 7;
    int c0 = cblk * 64;
    for (int i = 0; i < 36; ++i) {
        int f = i * 256 + threadIdx.x;
        int ch = f / 144, pos = f % 144;
        int r = pos / 12, s = pos % 12;
        int hh = ty * 8 + r - 2, ww = tx * 8 + s - 2;
        float v = 0.f;
        if (hh >= 0 && hh < 64 && ww >= 0 && ww < 64)
            v = x[((size_t)(b * NC + c0 + ch)) * 4096 + hh * 64 + ww];
        xs[f] = v;
    }
    __syncthreads();
    int lane = threadIdx.x & 63;
    int wid = threadIdx.x >> 6;
    int hy = lane >> 3, hx = lane & 7;
    float wreg[4][25];
    const float* kb = ker3 + ((size_t)(b * 64 + tile)) * 100 * 64 + lane;
#pragma unroll
    for (int g = 0; g < 4; ++g)
#pragma unroll
        for (int k = 0; k < 25; ++k)
            wreg[g][k] = kb[(g * 25 + k) * 64];
    int oy0 = (ty * 8 + hy) * 2;
    int ox0 = (tx * 8 + hx) * 2;
    for (int cc = wid * 16; cc < wid * 16 + 16; ++cc) {
        const float* xp = xs + cc * 144 + hy * 12 + hx;
        float xv[25];
#pragma unroll
        for (int i = 0; i < 5; ++i)
#pragma unroll
            for (int j = 0; j < 5; ++j)
                xv[i * 5 + j] = xp[i * 12 + j];
        float v00 = 0.f, v01 = 0.f, v10 = 0.f, v11 = 0.f;
#pragma unroll
        for (int k = 0; k < 25; ++k) {
            v00 = fmaf(xv[k], wreg[0][k], v00);
            v01 = fmaf(xv[k], wreg[1][k], v01);
            v10 = fmaf(xv[k], wreg[2][k], v10);
            v11 = fmaf(xv[k], wreg[3][k], v11);
        }
        size_t ob = ((size_t)(b * NC + c0 + cc) * 128 + oy0) * 128 + ox0;
        *reinterpret_cast<float2*>(&out[ob])       = make_float2(v00, v01);
        *reinterpret_cast<float2*>(&out[ob + 128]) = make_float2(v10, v11);
    }
}

extern "C" void kernel_launch(void* const* d_in, const int* in_sizes, int n_in,
                              void* d_out, int out_size, void* d_ws, size_t ws_size,
                              hipStream_t stream) {
    const float* x     = (const float*)d_in[0];
    const float* w_enc = (const float*)d_in[1];
    const float* b_enc = (const float*)d_in[2];
    const float* w_kp  = (const float*)d_in[3];
    const float* b_kp  = (const float*)d_in[4];
    float* out = (float*)d_out;

    float* ws   = (float*)d_ws;
    float* xc   = ws;                     // 2*64*4096      = 524288
    float* wr   = xc + 524288;            // 57600
    float* plog = wr + 57600;             // 2*2*4*25*4096  = 1638400
    float* ker3 = plog + 1638400;         // 2*64*100*64    = 819200

    reorder_wkp<<<225, 256, 0, stream>>>(w_kp, wr);
    encoder_kernel<<<256, 256, 0, stream>>>(x, w_enc, b_enc, xc);
    kp_conv_kernel<<<256, 256, 0, stream>>>(xc, wr, plog);
    softmax_kernel<<<128, 256, 0, stream>>>(plog, b_kp, ker3);
    gather_kernel<<<512, 256, 0, stream>>>(x, ker3, out);
}

// Round 2
// 129.102 us; speedup vs baseline: 1.0632x; 1.0632x over previous
//
#include <hip/hip_runtime.h>

// CARAFE upsample: B=2, C=256, H=W=64, S=2, K=5, COMP=64, KP=100
// encoder (1x1) -> kp conv (3x3, co-quartered, bf16 partials) -> combine+softmax -> gather

#define NB 2
#define NC 256
#define NCOMP 64

static __device__ __forceinline__ unsigned short f2bf(float f) {
    unsigned u = __float_as_uint(f);
    unsigned r = (u + 0x7fffu + ((u >> 16) & 1u)) >> 16;
    return (unsigned short)r;
}
static __device__ __forceinline__ float bf2f(unsigned short s) {
    return __uint_as_float(((unsigned)s) << 16);
}

// ---------------- W reorder: wr[g][co64][d][k2] ----------------
__global__ __launch_bounds__(256) void reorder_wkp(const float* __restrict__ w_kp,
                                                   float* __restrict__ wr) {
    int idx = blockIdx.x * 256 + threadIdx.x;
    if (idx >= 4 * 64 * 9 * 25) return;
    int k2 = idx % 25;
    int d  = (idx / 25) % 9;
    int co = (idx / 225) % 64;
    int g  = idx / 14400;
    wr[idx] = w_kp[((k2 * 4 + g) * 64 + co) * 9 + d];
}

// ---------------- A: encoder ----------------
// grid 256: (b, h, half); 256 thr: wl=tid&63, og=tid>>6 -> 8 outputs each
__global__ __launch_bounds__(256) void encoder_kernel(const float* __restrict__ x,
        const float* __restrict__ w_enc, const float* __restrict__ b_enc,
        float* __restrict__ xc) {
    __shared__ float xs[128 * 64];              // 32 KB: half the channels of one row
    __shared__ __align__(16) float wt[128 * 36];// transposed weights [c][o32 pad36]
    int bid = blockIdx.x;
    int half = bid & 1;
    int h = (bid >> 1) & 63;
    int b = bid >> 7;
    int tid = threadIdx.x;
    int wl = tid & 63;
    int og = tid >> 6;
    float acc[8];
#pragma unroll
    for (int k = 0; k < 8; ++k) acc[k] = 0.f;
    for (int p = 0; p < 2; ++p) {
        for (int i = 0; i < 32; ++i) {
            int f = i * 256 + tid;
            int c = f >> 6, w = f & 63;
            xs[f] = x[((size_t)(b * NC + p * 128 + c)) * 4096 + h * 64 + w];
        }
        for (int i = 0; i < 16; ++i) {
            int f = i * 256 + tid;
            int c = f & 127, o = f >> 7;
            wt[c * 36 + o] = w_enc[(half * 32 + o) * 256 + p * 128 + c];
        }
        __syncthreads();
#pragma unroll 4
        for (int c = 0; c < 128; ++c) {
            float xv = xs[c * 64 + wl];
            const float4* wp = (const float4*)(wt + c * 36 + og * 8);
            float4 wa = wp[0], wb = wp[1];
            acc[0] = fmaf(xv, wa.x, acc[0]);
            acc[1] = fmaf(xv, wa.y, acc[1]);
            acc[2] = fmaf(xv, wa.z, acc[2]);
            acc[3] = fmaf(xv, wa.w, acc[3]);
            acc[4] = fmaf(xv, wb.x, acc[4]);
            acc[5] = fmaf(xv, wb.y, acc[5]);
            acc[6] = fmaf(xv, wb.z, acc[6]);
            acc[7] = fmaf(xv, wb.w, acc[7]);
        }
        __syncthreads();
    }
    int o0 = half * 32 + og * 8;
#pragma unroll
    for (int k = 0; k < 8; ++k)
        xc[((size_t)(b * NCOMP + o0 + k)) * 4096 + h * 64 + wl] = acc[k] + b_enc[o0 + k];
}

// ---------------- B1: 3x3 conv partials (co-quartered), bf16 out ----------------
// grid 256: bid = ((b*8+tile)*4+g)*4+coq ; tile: 4 rowgroups(16) x 2 colgroups(32)
// 256 thr: hy=tid>>4 (0..15), hx2=tid&15 -> pixels (hy, 2*hx2) and (hy, 2*hx2+1)
// plogb[coq][b][g][k2][tileG][laneG]  (gather tiling), bf16
__global__ __launch_bounds__(256) void kp_conv_kernel(const float* __restrict__ xc,
        const float* __restrict__ wr, unsigned short* __restrict__ plogb) {
    __shared__ float xcs[16 * 18 * 37];             // 42.6 KB
    __shared__ __align__(16) float wks[16 * 9 * 28];// 16.1 KB
    int bid = blockIdx.x;
    int coq = bid & 3;
    int g   = (bid >> 2) & 3;
    int tile = (bid >> 4) & 7;
    int b   = bid >> 7;
    int trow = tile >> 1, tcol = tile & 1;
    int tid = threadIdx.x;
    // stage x tile with halo: rows trow*16-1 .. +16, cols tcol*32-1 .. +32
    for (int i = 0; i < 39; ++i) {
        int f = i * 256 + tid;
        if (f < 16 * 18 * 34) {
            int s = f % 34;
            int r = (f / 34) % 18;
            int co = f / 612;
            int gh = trow * 16 + r - 1, gw = tcol * 32 + s - 1;
            float v = 0.f;
            if (gh >= 0 && gh < 64 && gw >= 0 && gw < 64)
                v = xc[((size_t)(b * NCOMP + coq * 16 + co)) * 4096 + gh * 64 + gw];
            xcs[co * 666 + r * 37 + s] = v;
        }
    }
    // stage weights [co][d][k2 pad 28]
    for (int i = 0; i < 15; ++i) {
        int f = i * 256 + tid;
        if (f < 3600) {
            int k2 = f % 25;
            int d  = (f / 25) % 9;
            int co = f / 225;
            wks[co * 252 + d * 28 + k2] = wr[((g * 64 + coq * 16 + co) * 9 + d) * 25 + k2];
        }
    }
    __syncthreads();
    int hy = tid >> 4, hx2 = tid & 15;
    float acc0[25], acc1[25];
#pragma unroll
    for (int k = 0; k < 25; ++k) { acc0[k] = 0.f; acc1[k] = 0.f; }
#pragma unroll 1
    for (int co = 0; co < 16; ++co) {
        const float* xb = xcs + co * 666 + hy * 37 + 2 * hx2;
        float xr[3][4];
#pragma unroll
        for (int di = 0; di < 3; ++di)
#pragma unroll
            for (int dj = 0; dj < 4; ++dj)
                xr[di][dj] = xb[di * 37 + dj];
        const float* wb = wks + co * 252;
#pragma unroll
        for (int d = 0; d < 9; ++d) {
            float w[28];
            const float4* wq = (const float4*)(wb + d * 28);
#pragma unroll
            for (int q = 0; q < 7; ++q) ((float4*)w)[q] = wq[q];
            int di = d / 3, dj = d % 3;
            float xv0 = xr[di][dj], xv1 = xr[di][dj + 1];
#pragma unroll
            for (int k = 0; k < 25; ++k) {
                acc0[k] = fmaf(xv0, w[k], acc0[k]);
                acc1[k] = fmaf(xv1, w[k], acc1[k]);
            }
        }
    }
    int h = trow * 16 + hy, w0 = tcol * 32 + 2 * hx2;
    int tileG = (h >> 3) * 8 + (w0 >> 3);
    int laneG = (h & 7) * 8 + (w0 & 7);
    size_t sbase = (((size_t)(coq * 2 + b) * 4 + g) * 25) * 4096 + tileG * 64 + laneG;
#pragma unroll
    for (int k = 0; k < 25; ++k) {
        ushort2 pk;
        pk.x = f2bf(acc0[k]);
        pk.y = f2bf(acc1[k]);
        *reinterpret_cast<ushort2*>(plogb + sbase + (size_t)k * 4096) = pk;
    }
}

// ---------------- B2: combine 4 partials + bias + softmax -> ker3 ----------------
// grid 128: (b, tile); 256 thr: lane=tid&63, g=tid>>6
__global__ __launch_bounds__(256) void softmax_kernel(const unsigned short* __restrict__ plogb,
        const float* __restrict__ b_kp, float* __restrict__ ker3) {
    int bid = blockIdx.x;
    int tile = bid & 63;
    int b = bid >> 6;
    int lane = threadIdx.x & 63;
    int g = threadIdx.x >> 6;
    float l[25];
#pragma unroll
    for (int k = 0; k < 25; ++k) {
        float s = 0.f;
#pragma unroll
        for (int coq = 0; coq < 4; ++coq)
            s += bf2f(plogb[(((size_t)(coq * 2 + b) * 4 + g) * 25 + k) * 4096 + tile * 64 + lane]);
        l[k] = s + b_kp[k * 4 + g];
    }
    float m = l[0];
#pragma unroll
    for (int k = 1; k < 25; ++k) m = fmaxf(m, l[k]);
    float s = 0.f;
#pragma unroll
    for (int k = 0; k < 25; ++k) { l[k] = __expf(l[k] - m); s += l[k]; }
    float inv = 1.f / s;
    size_t o0 = (((size_t)(b * 64 + tile) * 4 + g) * 25) * 64 + lane;
#pragma unroll
    for (int k = 0; k < 25; ++k) ker3[o0 + (size_t)k * 64] = l[k] * inv;
}

// ---------------- C: gather ----------------
// grid 512: (b, tile8x8, cblk64); 256 thr = 4 waves (16 ch each), lane = low-res pixel
__global__ __launch_bounds__(256) void gather_kernel(const float* __restrict__ x,
        const float* __restrict__ ker3, float* __restrict__ out) {
    __shared__ float xs[64 * 144];   // [ch][12][12], 36.9 KB
    int bid = blockIdx.x;
    int cblk = bid & 3;
    int tile = (bid >> 2) & 63;
    int b = bid >> 8;
    int ty = tile >> 3, tx = tile & 7;
    int c0 = cblk * 64;
    for (int i = 0; i < 36; ++i) {
        int f = i * 256 + threadIdx.x;
        int ch = f / 144, pos = f % 144;
        int r = pos / 12, s = pos % 12;
        int hh = ty * 8 + r - 2, ww = tx * 8 + s - 2;
        float v = 0.f;
        if (hh >= 0 && hh < 64 && ww >= 0 && ww < 64)
            v = x[((size_t)(b * NC + c0 + ch)) * 4096 + hh * 64 + ww];
        xs[f] = v;
    }
    __syncthreads();
    int lane = threadIdx.x & 63;
    int wid = threadIdx.x >> 6;
    int hy = lane >> 3, hx = lane & 7;
    float wreg[4][25];
    const float* kb = ker3 + ((size_t)(b * 64 + tile)) * 100 * 64 + lane;
#pragma unroll
    for (int g = 0; g < 4; ++g)
#pragma unroll
        for (int k = 0; k < 25; ++k)
            wreg[g][k] = kb[(g * 25 + k) * 64];
    int oy0 = (ty * 8 + hy) * 2;
    int ox0 = (tx * 8 + hx) * 2;
    for (int cc = wid * 16; cc < wid * 16 + 16; ++cc) {
        const float* xp = xs + cc * 144 + hy * 12 + hx;
        float xv[25];
#pragma unroll
        for (int i = 0; i < 5; ++i)
#pragma unroll
            for (int j = 0; j < 5; ++j)
                xv[i * 5 + j] = xp[i * 12 + j];
        float v00 = 0.f, v01 = 0.f, v10 = 0.f, v11 = 0.f;
#pragma unroll
        for (int k = 0; k < 25; ++k) {
            v00 = fmaf(xv[k], wreg[0][k], v00);
            v01 = fmaf(xv[k], wreg[1][k], v01);
            v10 = fmaf(xv[k], wreg[2][k], v10);
            v11 = fmaf(xv[k], wreg[3][k], v11);
        }
        size_t ob = ((size_t)(b * NC + c0 + cc) * 128 + oy0) * 128 + ox0;
        *reinterpret_cast<float2*>(&out[ob])       = make_float2(v00, v01);
        *reinterpret_cast<float2*>(&out[ob + 128]) = make_float2(v10, v11);
    }
}

extern "C" void kernel_launch(void* const* d_in, const int* in_sizes, int n_in,
                              void* d_out, int out_size, void* d_ws, size_t ws_size,
                              hipStream_t stream) {
    const float* x     = (const float*)d_in[0];
    const float* w_enc = (const float*)d_in[1];
    const float* b_enc = (const float*)d_in[2];
    const float* w_kp  = (const float*)d_in[3];
    const float* b_kp  = (const float*)d_in[4];
    float* out = (float*)d_out;

    float* ws   = (float*)d_ws;
    float* xc   = ws;                        // 2*64*4096   = 524288 f
    float* wr   = xc + 524288;               // 57600 f
    float* ker3 = wr + 57600;                // 2*64*100*64 = 819200 f
    unsigned short* plogb = (unsigned short*)(ker3 + 819200);  // 4*2*4*25*4096 bf16

    reorder_wkp<<<225, 256, 0, stream>>>(w_kp, wr);
    encoder_kernel<<<256, 256, 0, stream>>>(x, w_enc, b_enc, xc);
    kp_conv_kernel<<<256, 256, 0, stream>>>(xc, wr, plogb);
    softmax_kernel<<<128, 256, 0, stream>>>(plogb, b_kp, ker3);
    gather_kernel<<<512, 256, 0, stream>>>(x, ker3, out);
}

// Round 4
// 107.420 us; speedup vs baseline: 1.2778x; 1.2018x over previous
//
#include <hip/hip_runtime.h>

// CARAFE upsample: B=2, C=256, H=W=64, S=2, K=5, COMP=64, KP=100
// prep -> encoder (1x1, s_load w) -> kp conv (3x3, s_load w, bf16 partials)
//      -> softmax (emits fp16 dot2-ready weights) -> gather (fp16 dot2)

#define NB 2
#define NC 256
#define NCOMP 64

typedef _Float16 h2 __attribute__((ext_vector_type(2)));
typedef __fp16 f16x2 __attribute__((ext_vector_type(2)));
union U32H2 { unsigned u; h2 h; f16x2 f; };
static __device__ __forceinline__ h2 u2h(unsigned u) { U32H2 t; t.u = u; return t.h; }

static __device__ __forceinline__ unsigned short f2bf(float f) {
    unsigned u = __float_as_uint(f);
    return (unsigned short)((u + 0x7fffu + ((u >> 16) & 1u)) >> 16);
}
static __device__ __forceinline__ float bf2f(unsigned short s) {
    return __uint_as_float(((unsigned)s) << 16);
}

// ---------------- prep: wr[g][co64][d][k2] + wt[half][c][o32] ----------------
__global__ __launch_bounds__(256) void prep_weights(const float* __restrict__ w_kp,
        const float* __restrict__ w_enc, float* __restrict__ wr, float* __restrict__ wt) {
    int idx = blockIdx.x * 256 + threadIdx.x;
    if (idx < 57600) {
        int k2 = idx % 25;
        int d  = (idx / 25) % 9;
        int co = (idx / 225) % 64;
        int g  = idx / 14400;
        wr[idx] = w_kp[((k2 * 4 + g) * 64 + co) * 9 + d];
    }
    int j = idx - 57600;
    if (j >= 0 && j < 16384) {
        int o32 = j % 32;
        int c = (j / 32) % 256;
        int half = j / 8192;
        wt[j] = w_enc[(half * 32 + o32) * 256 + c];
    }
}

// ---------------- A: encoder ----------------
// grid 256: (b, h, half); thread: wl=tid&63, og=wave (8 outputs). w via s_load, x global.
__global__ __launch_bounds__(256) void encoder_kernel(const float* __restrict__ x,
        const float* __restrict__ wt, const float* __restrict__ b_enc,
        float* __restrict__ xc) {
    int bid = blockIdx.x;
    int half = bid & 1;
    int h = (bid >> 1) & 63;
    int b = bid >> 7;
    int wl = threadIdx.x & 63;
    int og = __builtin_amdgcn_readfirstlane(threadIdx.x >> 6);
    const float* xrow = x + ((size_t)(b * NC)) * 4096 + h * 64 + wl;
    const float* wrow = wt + half * 8192 + og * 8;
    float acc[8] = {0.f, 0.f, 0.f, 0.f, 0.f, 0.f, 0.f, 0.f};
#pragma unroll 4
    for (int c = 0; c < 256; ++c) {
        float xv = xrow[(size_t)c * 4096];
        const float* wp = wrow + c * 32;
#pragma unroll
        for (int k = 0; k < 8; ++k) acc[k] = fmaf(xv, wp[k], acc[k]);
    }
    int o0 = half * 32 + og * 8;
#pragma unroll
    for (int k = 0; k < 8; ++k)
        xc[((size_t)(b * NCOMP + o0 + k)) * 4096 + h * 64 + wl] = acc[k] + b_enc[o0 + k];
}

// ---------------- B1: 3x3 conv partials, weights via scalar pipe ----------------
// grid 512: bid = ((b*16 + tile)*4 + g)*4 + coq ; tile 16x16 px, 1 px/thread
// plogb[((coq*2+b)*4+g)*25 + k2][h*64+w]  bf16
__global__ __launch_bounds__(256) void kp_conv_kernel(const float* __restrict__ xc,
        const float* __restrict__ wr, unsigned short* __restrict__ plogb) {
    __shared__ float xcs[16 * 18 * 19];   // [co][r18][s pad19], 21.9 KB
    int bid = blockIdx.x;
    int coq = bid & 3;
    int g = (bid >> 2) & 3;
    int tile = (bid >> 4) & 15;
    int b = bid >> 8;
    int trow = tile >> 2, tcol = tile & 3;
    int tid = threadIdx.x;
    for (int i = 0; i < 21; ++i) {
        int f = i * 256 + tid;
        if (f < 16 * 18 * 18) {
            int s = f % 18, r = (f / 18) % 18, co = f / 324;
            int gh = trow * 16 + r - 1, gw = tcol * 16 + s - 1;
            float v = 0.f;
            if (gh >= 0 && gh < 64 && gw >= 0 && gw < 64)
                v = xc[((size_t)(b * NCOMP + coq * 16 + co)) * 4096 + gh * 64 + gw];
            xcs[co * 342 + r * 19 + s] = v;
        }
    }
    __syncthreads();
    int hy = tid >> 4, hx = tid & 15;
    float acc[25];
#pragma unroll
    for (int k = 0; k < 25; ++k) acc[k] = 0.f;
    const float* wbase = wr + (size_t)(g * 64 + coq * 16) * 225;
#pragma unroll 1
    for (int co = 0; co < 16; ++co) {
        const float* xb = xcs + co * 342 + hy * 19 + hx;
        float xr[9];
#pragma unroll
        for (int di = 0; di < 3; ++di)
#pragma unroll
            for (int dj = 0; dj < 3; ++dj)
                xr[di * 3 + dj] = xb[di * 19 + dj];
        const float* wp = wbase + co * 225;   // scalar address -> s_load
#pragma unroll
        for (int d = 0; d < 9; ++d) {
            float xv = xr[d];
#pragma unroll
            for (int k = 0; k < 25; ++k)
                acc[k] = fmaf(xv, wp[d * 25 + k], acc[k]);
        }
    }
    int h = trow * 16 + hy, w = tcol * 16 + hx;
    size_t base = ((size_t)((coq * 2 + b) * 4 + g) * 25) * 4096 + h * 64 + w;
#pragma unroll
    for (int k = 0; k < 25; ++k)
        plogb[base + (size_t)k * 4096] = f2bf(acc[k]);
}

// ---------------- B2: combine + softmax -> kerh fp16 pairs ----------------
// kerh[b][t32][pxsel2][g4][i5][j3][lane64] u32(half2)
// j<2: (w[i5+2j], w[i5+2j+1]); j=2: px0 (w4,0), px1 (0,w4)
__global__ __launch_bounds__(128) void softmax_kernel(const unsigned short* __restrict__ plogb,
        const float* __restrict__ b_kp, unsigned* __restrict__ kerh) {
    int gt = blockIdx.x * 128 + threadIdx.x;   // 32768 = b2 * g4 * px4096
    int b = gt >> 14;
    int g = (gt >> 12) & 3;
    int px = gt & 4095;
    float l[25];
#pragma unroll
    for (int k = 0; k < 25; ++k) {
        float s = 0.f;
#pragma unroll
        for (int coq = 0; coq < 4; ++coq)
            s += bf2f(plogb[((size_t)((coq * 2 + b) * 4 + g) * 25 + k) * 4096 + px]);
        l[k] = s + b_kp[k * 4 + g];
    }
    float m = l[0];
#pragma unroll
    for (int k = 1; k < 25; ++k) m = fmaxf(m, l[k]);
    float s = 0.f;
#pragma unroll
    for (int k = 0; k < 25; ++k) { l[k] = __expf(l[k] - m); s += l[k]; }
    float inv = 1.f / s;
#pragma unroll
    for (int k = 0; k < 25; ++k) l[k] *= inv;
    int h = px >> 6, w = px & 63;
    int t = (h >> 3) * 4 + (w >> 4);
    int lane = (h & 7) * 8 + ((w & 15) >> 1);
    int pxsel = w & 1;
    unsigned* kb = kerh + (((size_t)(b * 32 + t) * 2 + pxsel) * 4) * 15 * 64 + lane;
#pragma unroll
    for (int i = 0; i < 5; ++i) {
        U32H2 u0, u1, u2;
        u0.f = __builtin_amdgcn_cvt_pkrtz(l[i * 5 + 0], l[i * 5 + 1]);
        u1.f = __builtin_amdgcn_cvt_pkrtz(l[i * 5 + 2], l[i * 5 + 3]);
        if (pxsel) u2.f = __builtin_amdgcn_cvt_pkrtz(0.f, l[i * 5 + 4]);
        else       u2.f = __builtin_amdgcn_cvt_pkrtz(l[i * 5 + 4], 0.f);
        kb[((g * 5 + i) * 3 + 0) * 64] = u0.u;
        kb[((g * 5 + i) * 3 + 1) * 64] = u1.u;
        kb[((g * 5 + i) * 3 + 2) * 64] = u2.u;
    }
}

// ---------------- C: gather, fp16 dot2 ----------------
// grid 1024: bid = (b*32 + t)*16 + cblk16; tile 8x16 px; lane=(hy8,hxp8), px-pair
__global__ __launch_bounds__(256) void gather_kernel(const float* __restrict__ x,
        const unsigned* __restrict__ kerh, float* __restrict__ out) {
    __shared__ unsigned xs[16 * 132];   // [ch][r12][p10 pad11] half2, 8.4 KB
    int bid = blockIdx.x;
    int cblk = bid & 15;
    int t = (bid >> 4) & 31;
    int b = bid >> 9;
    int ty = t >> 2, tx = t & 3;
    int c0 = cblk * 16;
    int tid = threadIdx.x;
    for (int i = 0; i < 8; ++i) {
        int f = i * 256 + tid;
        if (f < 1920) {
            int p = f % 10;
            int r = (f / 10) % 12;
            int ch = f / 120;
            int gh = ty * 8 + r - 2;
            int gw = tx * 16 + 2 * p - 2;
            float v0 = 0.f, v1 = 0.f;
            if (gh >= 0 && gh < 64) {
                const float* xp = x + ((size_t)(b * NC + c0 + ch)) * 4096 + gh * 64;
                if (gw >= 0 && gw < 64) v0 = xp[gw];
                if (gw + 1 >= 0 && gw + 1 < 64) v1 = xp[gw + 1];
            }
            U32H2 u; u.f = __builtin_amdgcn_cvt_pkrtz(v0, v1);
            xs[ch * 132 + r * 11 + p] = u.u;
        }
    }
    __syncthreads();
    int lane = tid & 63;
    int wid = tid >> 6;
    int hy = lane >> 3, hxp = lane & 7;
    const unsigned* kb0 = kerh + ((size_t)(b * 32 + t) * 2) * 3840 + lane;
    const unsigned* kb1 = kb0 + 3840;
    unsigned wv[4][5][3];
    float r0[4][4], r1[4][4];
    // ---- phase px0 (w even) ----
#pragma unroll
    for (int g = 0; g < 4; ++g)
#pragma unroll
        for (int i = 0; i < 5; ++i)
#pragma unroll
            for (int j = 0; j < 3; ++j)
                wv[g][i][j] = kb0[((g * 5 + i) * 3 + j) * 64];
#pragma unroll
    for (int ch = 0; ch < 4; ++ch) {
        const unsigned* xb = xs + (wid * 4 + ch) * 132 + hy * 11 + hxp;
        float a0 = 0.f, a1 = 0.f, a2 = 0.f, a3 = 0.f;
#pragma unroll
        for (int i = 0; i < 5; ++i) {
            unsigned A = xb[i * 11], B = xb[i * 11 + 1], C = xb[i * 11 + 2];
            a0 = __builtin_amdgcn_fdot2(u2h(A), u2h(wv[0][i][0]), a0, false);
            a0 = __builtin_amdgcn_fdot2(u2h(B), u2h(wv[0][i][1]), a0, false);
            a0 = __builtin_amdgcn_fdot2(u2h(C), u2h(wv[0][i][2]), a0, false);
            a1 = __builtin_amdgcn_fdot2(u2h(A), u2h(wv[1][i][0]), a1, false);
            a1 = __builtin_amdgcn_fdot2(u2h(B), u2h(wv[1][i][1]), a1, false);
            a1 = __builtin_amdgcn_fdot2(u2h(C), u2h(wv[1][i][2]), a1, false);
            a2 = __builtin_amdgcn_fdot2(u2h(A), u2h(wv[2][i][0]), a2, false);
            a2 = __builtin_amdgcn_fdot2(u2h(B), u2h(wv[2][i][1]), a2, false);
            a2 = __builtin_amdgcn_fdot2(u2h(C), u2h(wv[2][i][2]), a2, false);
            a3 = __builtin_amdgcn_fdot2(u2h(A), u2h(wv[3][i][0]), a3, false);
            a3 = __builtin_amdgcn_fdot2(u2h(B), u2h(wv[3][i][1]), a3, false);
            a3 = __builtin_amdgcn_fdot2(u2h(C), u2h(wv[3][i][2]), a3, false);
        }
        r0[ch][0] = a0; r0[ch][1] = a1; r0[ch][2] = a2; r0[ch][3] = a3;
    }
    // ---- phase px1 (w odd) ----
#pragma unroll
    for (int g = 0; g < 4; ++g)
#pragma unroll
        for (int i = 0; i < 5; ++i)
#pragma unroll
            for (int j = 0; j < 3; ++j)
                wv[g][i][j] = kb1[((g * 5 + i) * 3 + j) * 64];
#pragma unroll
    for (int ch = 0; ch < 4; ++ch) {
        const unsigned* xb = xs + (wid * 4 + ch) * 132 + hy * 11 + hxp;
        float a0 = 0.f, a1 = 0.f, a2 = 0.f, a3 = 0.f;
#pragma unroll
        for (int i = 0; i < 5; ++i) {
            unsigned A = xb[i * 11], B = xb[i * 11 + 1], C = xb[i * 11 + 2];
            unsigned P1 = (A >> 16) | (B << 16);   // (c1,c2)
            unsigned P2 = (B >> 16) | (C << 16);   // (c3,c4)
            a0 = __builtin_amdgcn_fdot2(u2h(P1), u2h(wv[0][i][0]), a0, false);
            a0 = __builtin_amdgcn_fdot2(u2h(P2), u2h(wv[0][i][1]), a0, false);
            a0 = __builtin_amdgcn_fdot2(u2h(C),  u2h(wv[0][i][2]), a0, false);
            a1 = __builtin_amdgcn_fdot2(u2h(P1), u2h(wv[1][i][0]), a1, false);
            a1 = __builtin_amdgcn_fdot2(u2h(P2), u2h(wv[1][i][1]), a1, false);
            a1 = __builtin_amdgcn_fdot2(u2h(C),  u2h(wv[1][i][2]), a1, false);
            a2 = __builtin_amdgcn_fdot2(u2h(P1), u2h(wv[2][i][0]), a2, false);
            a2 = __builtin_amdgcn_fdot2(u2h(P2), u2h(wv[2][i][1]), a2, false);
            a2 = __builtin_amdgcn_fdot2(u2h(C),  u2h(wv[2][i][2]), a2, false);
            a3 = __builtin_amdgcn_fdot2(u2h(P1), u2h(wv[3][i][0]), a3, false);
            a3 = __builtin_amdgcn_fdot2(u2h(P2), u2h(wv[3][i][1]), a3, false);
            a3 = __builtin_amdgcn_fdot2(u2h(C),  u2h(wv[3][i][2]), a3, false);
        }
        r1[ch][0] = a0; r1[ch][1] = a1; r1[ch][2] = a2; r1[ch][3] = a3;
    }
    // ---- store: float4 per out-row per channel ----
    int oy0 = (ty * 8 + hy) * 2;
    int ox0 = tx * 32 + 4 * hxp;
#pragma unroll
    for (int ch = 0; ch < 4; ++ch) {
        int cc = c0 + wid * 4 + ch;
        float* rb = out + ((size_t)(b * NC + cc) * 128 + oy0) * 128 + ox0;
        float4 f0 = make_float4(r0[ch][0], r0[ch][1], r1[ch][0], r1[ch][1]);
        float4 f1 = make_float4(r0[ch][2], r0[ch][3], r1[ch][2], r1[ch][3]);
        *reinterpret_cast<float4*>(rb)       = f0;
        *reinterpret_cast<float4*>(rb + 128) = f1;
    }
}

extern "C" void kernel_launch(void* const* d_in, const int* in_sizes, int n_in,
                              void* d_out, int out_size, void* d_ws, size_t ws_size,
                              hipStream_t stream) {
    const float* x     = (const float*)d_in[0];
    const float* w_enc = (const float*)d_in[1];
    const float* b_enc = (const float*)d_in[2];
    const float* w_kp  = (const float*)d_in[3];
    const float* b_kp  = (const float*)d_in[4];
    float* out = (float*)d_out;

    float* ws = (float*)d_ws;
    float* xc = ws;                          // 524288 f
    float* wr = xc + 524288;                 // 57600 f
    float* wt = wr + 57600;                  // 16384 f
    unsigned short* plogb = (unsigned short*)(wt + 16384);      // 800*4096 bf16 = 6.55 MB
    unsigned* kerh = (unsigned*)((char*)d_ws + 2393088 + 6553600); // 983040 u32 = 3.93 MB

    prep_weights<<<289, 256, 0, stream>>>(w_kp, w_enc, wr, wt);
    encoder_kernel<<<256, 256, 0, stream>>>(x, wt, b_enc, xc);
    kp_conv_kernel<<<512, 256, 0, stream>>>(xc, wr, plogb);
    softmax_kernel<<<256, 128, 0, stream>>>(plogb, b_kp, kerh);
    gather_kernel<<<1024, 256, 0, stream>>>(x, kerh, out);
}

// Round 5
// 68.421 us; speedup vs baseline: 2.0061x; 1.5700x over previous
//
#include <hip/hip_runtime.h>

// CARAFE upsample: B=2, C=256, H=W=64, S=2, K=5, COMP=64, KP=100
// prep -> encoder (1x1, fp16-pair out) -> kp conv (3x3 fp16 dot2, fused softmax)
//      -> gather (fp16 dot2)

#define NB 2
#define NC 256

typedef _Float16 h2v __attribute__((ext_vector_type(2)));
typedef __fp16 f16x2 __attribute__((ext_vector_type(2)));
union U32H2 { unsigned u; h2v h; f16x2 f; };
static __device__ __forceinline__ h2v u2h(unsigned u) { U32H2 t; t.u = u; return t.h; }
static __device__ __forceinline__ unsigned pkh(float a, float b) {
    U32H2 t; t.f = __builtin_amdgcn_cvt_pkrtz(a, b); return t.u;
}

// ---------------- prep: whr[g][cp32][d9][k2 pad28] fp16-pairs + wt[half][c][o32] ----------------
__global__ __launch_bounds__(256) void prep_weights(const float* __restrict__ w_kp,
        const float* __restrict__ w_enc, unsigned* __restrict__ whr, float* __restrict__ wt) {
    int idx = blockIdx.x * 256 + threadIdx.x;
    if (idx < 32256) {
        int k = idx % 28;
        int d = (idx / 28) % 9;
        int cp = (idx / 252) % 32;
        int g = idx / 8064;
        unsigned val = 0;
        if (k < 25) {
            float a = w_kp[((size_t)(k * 4 + g) * 64 + 2 * cp) * 9 + d];
            float b = w_kp[((size_t)(k * 4 + g) * 64 + 2 * cp + 1) * 9 + d];
            val = pkh(a, b);
        }
        whr[idx] = val;
    }
    int j = idx - 32256;
    if (j >= 0 && j < 16384) {
        int o32 = j % 32;
        int c = (j / 32) % 256;
        int half = j / 8192;
        wt[j] = w_enc[(half * 32 + o32) * 256 + c];
    }
}

// ---------------- A: encoder -> xch[b][cp32][px4096] fp16 pairs ----------------
// grid 256: (b, h, half); 512 thr = 8 waves; wave og -> 4 outputs; x row staged in LDS
__global__ __launch_bounds__(512) void encoder_kernel(const float* __restrict__ x,
        const float* __restrict__ wt, const float* __restrict__ b_enc,
        unsigned* __restrict__ xch) {
    __shared__ float xs[256 * 64];   // 64 KB
    int bid = blockIdx.x;
    int half = bid & 1;
    int h = (bid >> 1) & 63;
    int b = bid >> 7;
    int tid = threadIdx.x;
    for (int i = 0; i < 32; ++i) {
        int f = i * 512 + tid;
        int c = f >> 6, w = f & 63;
        xs[f] = x[((size_t)(b * NC + c)) * 4096 + h * 64 + w];
    }
    __syncthreads();
    int wl = tid & 63;
    int og = __builtin_amdgcn_readfirstlane(tid >> 6);   // 0..7
    const float* wrow = wt + half * 8192 + og * 4;
    float a0 = 0.f, a1 = 0.f, a2 = 0.f, a3 = 0.f;
#pragma unroll 8
    for (int c = 0; c < 256; ++c) {
        float xv = xs[c * 64 + wl];
        const float* wp = wrow + c * 32;
        a0 = fmaf(xv, wp[0], a0);
        a1 = fmaf(xv, wp[1], a1);
        a2 = fmaf(xv, wp[2], a2);
        a3 = fmaf(xv, wp[3], a3);
    }
    int o0 = half * 32 + og * 4;
    a0 += b_enc[o0 + 0]; a1 += b_enc[o0 + 1]; a2 += b_enc[o0 + 2]; a3 += b_enc[o0 + 3];
    int cp0 = o0 >> 1;
    xch[((size_t)(b * 32 + cp0)) * 4096 + h * 64 + wl]     = pkh(a0, a1);
    xch[((size_t)(b * 32 + cp0 + 1)) * 4096 + h * 64 + wl] = pkh(a2, a3);
}

// ---------------- B: kp conv (fp16 dot2) + fused softmax -> kerh ----------------
// grid 512: bid = ((b*64 + tile)*4 + g); tile 8x8 px; 256 thr: lane=px, wave=coq
__global__ __launch_bounds__(256) void kp_conv_kernel(const unsigned* __restrict__ xch,
        const unsigned* __restrict__ whr, const float* __restrict__ b_kp,
        unsigned* __restrict__ kerh) {
    __shared__ unsigned wlds[8064];   // [cp32][d9][k pad28], 32.3 KB
    __shared__ unsigned xcs[3840];    // [cp32][r10][s pad12], 15.4 KB
    __shared__ float red[6400];       // [coq4][k25][lane64], 25.6 KB
    int bid = blockIdx.x;
    int g = bid & 3;
    int tile = (bid >> 2) & 63;
    int b = bid >> 8;
    int trow = tile >> 3, tcol = tile & 7;
    int tid = threadIdx.x;
    for (int i = 0; i < 32; ++i) {
        int f = i * 256 + tid;
        if (f < 8064) wlds[f] = whr[g * 8064 + f];
    }
    for (int i = 0; i < 15; ++i) {
        int f = i * 256 + tid;
        if (f < 3840) {
            int s = f % 12;
            int r = (f / 12) % 10;
            int cp = f / 120;
            unsigned v = 0;
            int gh = trow * 8 + r - 1, gw = tcol * 8 + s - 1;
            if (s < 10 && gh >= 0 && gh < 64 && gw >= 0 && gw < 64)
                v = xch[((size_t)(b * 32 + cp)) * 4096 + gh * 64 + gw];
            xcs[f] = v;
        }
    }
    __syncthreads();
    int lane = tid & 63;
    int coq = tid >> 6;
    int hy = lane >> 3, hx = lane & 7;
    float acc[25];
#pragma unroll
    for (int k = 0; k < 25; ++k) acc[k] = 0.f;
#pragma unroll 1
    for (int ci = 0; ci < 8; ++ci) {
        int cp = coq * 8 + ci;
        const unsigned* xb = xcs + cp * 120 + hy * 12 + hx;
        unsigned xwin[9];
#pragma unroll
        for (int di = 0; di < 3; ++di)
#pragma unroll
            for (int dj = 0; dj < 3; ++dj)
                xwin[di * 3 + dj] = xb[di * 12 + dj];
        const uint4* wq = (const uint4*)(wlds + cp * 252);
#pragma unroll
        for (int d = 0; d < 9; ++d) {
            union { uint4 v[7]; unsigned w[28]; } W;
#pragma unroll
            for (int q = 0; q < 7; ++q) W.v[q] = wq[d * 7 + q];
            h2v xv = u2h(xwin[d]);
#pragma unroll
            for (int k = 0; k < 25; ++k)
                acc[k] = __builtin_amdgcn_fdot2(xv, u2h(W.w[k]), acc[k], false);
        }
    }
#pragma unroll
    for (int k = 0; k < 25; ++k) red[coq * 1600 + k * 64 + lane] = acc[k];
    __syncthreads();
    if (coq == 0) {
        float l[25];
#pragma unroll
        for (int k = 0; k < 25; ++k)
            l[k] = red[k * 64 + lane] + red[1600 + k * 64 + lane]
                 + red[3200 + k * 64 + lane] + red[4800 + k * 64 + lane]
                 + b_kp[k * 4 + g];
        float m = l[0];
#pragma unroll
        for (int k = 1; k < 25; ++k) m = fmaxf(m, l[k]);
        float s = 0.f;
#pragma unroll
        for (int k = 0; k < 25; ++k) { l[k] = __expf(l[k] - m); s += l[k]; }
        float inv = 1.f / s;
#pragma unroll
        for (int k = 0; k < 25; ++k) l[k] *= inv;
        int t = trow * 4 + (tcol >> 1);
        int lg = hy * 8 + (tcol & 1) * 4 + (hx >> 1);
        int pxsel = hx & 1;
        unsigned* kb = kerh + ((size_t)((b * 32 + t) * 2 + pxsel)) * 3840 + lg;
#pragma unroll
        for (int i = 0; i < 5; ++i) {
            unsigned u0 = pkh(l[i * 5 + 0], l[i * 5 + 1]);
            unsigned u1 = pkh(l[i * 5 + 2], l[i * 5 + 3]);
            unsigned u2 = pxsel ? pkh(0.f, l[i * 5 + 4]) : pkh(l[i * 5 + 4], 0.f);
            kb[((g * 5 + i) * 3 + 0) * 64] = u0;
            kb[((g * 5 + i) * 3 + 1) * 64] = u1;
            kb[((g * 5 + i) * 3 + 2) * 64] = u2;
        }
    }
}

// ---------------- C: gather, fp16 dot2 ----------------
// grid 1024: bid = (b*32 + t)*16 + cblk16; tile 8x16 px; lane=(hy8,hxp8), px-pair
__global__ __launch_bounds__(256) void gather_kernel(const float* __restrict__ x,
        const unsigned* __restrict__ kerh, float* __restrict__ out) {
    __shared__ unsigned xs[16 * 132];   // [ch][r12][p10 pad11] half2, 8.4 KB
    int bid = blockIdx.x;
    int cblk = bid & 15;
    int t = (bid >> 4) & 31;
    int b = bid >> 9;
    int ty = t >> 2, tx = t & 3;
    int c0 = cblk * 16;
    int tid = threadIdx.x;
    for (int i = 0; i < 8; ++i) {
        int f = i * 256 + tid;
        if (f < 1920) {
            int p = f % 10;
            int r = (f / 10) % 12;
            int ch = f / 120;
            int gh = ty * 8 + r - 2;
            int gw = tx * 16 + 2 * p - 2;
            float v0 = 0.f, v1 = 0.f;
            if (gh >= 0 && gh < 64) {
                const float* xp = x + ((size_t)(b * NC + c0 + ch)) * 4096 + gh * 64;
                if (gw >= 0 && gw < 64) v0 = xp[gw];
                if (gw + 1 >= 0 && gw + 1 < 64) v1 = xp[gw + 1];
            }
            xs[ch * 132 + r * 11 + p] = pkh(v0, v1);
        }
    }
    __syncthreads();
    int lane = tid & 63;
    int wid = tid >> 6;
    int hy = lane >> 3, hxp = lane & 7;
    const unsigned* kb0 = kerh + ((size_t)(b * 32 + t) * 2) * 3840 + lane;
    const unsigned* kb1 = kb0 + 3840;
    unsigned wv[4][5][3];
    float r0[4][4], r1[4][4];
    // ---- phase px0 (w even) ----
#pragma unroll
    for (int g = 0; g < 4; ++g)
#pragma unroll
        for (int i = 0; i < 5; ++i)
#pragma unroll
            for (int j = 0; j < 3; ++j)
                wv[g][i][j] = kb0[((g * 5 + i) * 3 + j) * 64];
#pragma unroll
    for (int ch = 0; ch < 4; ++ch) {
        const unsigned* xb = xs + (wid * 4 + ch) * 132 + hy * 11 + hxp;
        float a0 = 0.f, a1 = 0.f, a2 = 0.f, a3 = 0.f;
#pragma unroll
        for (int i = 0; i < 5; ++i) {
            unsigned A = xb[i * 11], B = xb[i * 11 + 1], C = xb[i * 11 + 2];
            a0 = __builtin_amdgcn_fdot2(u2h(A), u2h(wv[0][i][0]), a0, false);
            a0 = __builtin_amdgcn_fdot2(u2h(B), u2h(wv[0][i][1]), a0, false);
            a0 = __builtin_amdgcn_fdot2(u2h(C), u2h(wv[0][i][2]), a0, false);
            a1 = __builtin_amdgcn_fdot2(u2h(A), u2h(wv[1][i][0]), a1, false);
            a1 = __builtin_amdgcn_fdot2(u2h(B), u2h(wv[1][i][1]), a1, false);
            a1 = __builtin_amdgcn_fdot2(u2h(C), u2h(wv[1][i][2]), a1, false);
            a2 = __builtin_amdgcn_fdot2(u2h(A), u2h(wv[2][i][0]), a2, false);
            a2 = __builtin_amdgcn_fdot2(u2h(B), u2h(wv[2][i][1]), a2, false);
            a2 = __builtin_amdgcn_fdot2(u2h(C), u2h(wv[2][i][2]), a2, false);
            a3 = __builtin_amdgcn_fdot2(u2h(A), u2h(wv[3][i][0]), a3, false);
            a3 = __builtin_amdgcn_fdot2(u2h(B), u2h(wv[3][i][1]), a3, false);
            a3 = __builtin_amdgcn_fdot2(u2h(C), u2h(wv[3][i][2]), a3, false);
        }
        r0[ch][0] = a0; r0[ch][1] = a1; r0[ch][2] = a2; r0[ch][3] = a3;
    }
    // ---- phase px1 (w odd) ----
#pragma unroll
    for (int g = 0; g < 4; ++g)
#pragma unroll
        for (int i = 0; i < 5; ++i)
#pragma unroll
            for (int j = 0; j < 3; ++j)
                wv[g][i][j] = kb1[((g * 5 + i) * 3 + j) * 64];
#pragma unroll
    for (int ch = 0; ch < 4; ++ch) {
        const unsigned* xb = xs + (wid * 4 + ch) * 132 + hy * 11 + hxp;
        float a0 = 0.f, a1 = 0.f, a2 = 0.f, a3 = 0.f;
#pragma unroll
        for (int i = 0; i < 5; ++i) {
            unsigned A = xb[i * 11], B = xb[i * 11 + 1], C = xb[i * 11 + 2];
            unsigned P1 = (A >> 16) | (B << 16);
            unsigned P2 = (B >> 16) | (C << 16);
            a0 = __builtin_amdgcn_fdot2(u2h(P1), u2h(wv[0][i][0]), a0, false);
            a0 = __builtin_amdgcn_fdot2(u2h(P2), u2h(wv[0][i][1]), a0, false);
            a0 = __builtin_amdgcn_fdot2(u2h(C),  u2h(wv[0][i][2]), a0, false);
            a1 = __builtin_amdgcn_fdot2(u2h(P1), u2h(wv[1][i][0]), a1, false);
            a1 = __builtin_amdgcn_fdot2(u2h(P2), u2h(wv[1][i][1]), a1, false);
            a1 = __builtin_amdgcn_fdot2(u2h(C),  u2h(wv[1][i][2]), a1, false);
            a2 = __builtin_amdgcn_fdot2(u2h(P1), u2h(wv[2][i][0]), a2, false);
            a2 = __builtin_amdgcn_fdot2(u2h(P2), u2h(wv[2][i][1]), a2, false);
            a2 = __builtin_amdgcn_fdot2(u2h(C),  u2h(wv[2][i][2]), a2, false);
            a3 = __builtin_amdgcn_fdot2(u2h(P1), u2h(wv[3][i][0]), a3, false);
            a3 = __builtin_amdgcn_fdot2(u2h(P2), u2h(wv[3][i][1]), a3, false);
            a3 = __builtin_amdgcn_fdot2(u2h(C),  u2h(wv[3][i][2]), a3, false);
        }
        r1[ch][0] = a0; r1[ch][1] = a1; r1[ch][2] = a2; r1[ch][3] = a3;
    }
    int oy0 = (ty * 8 + hy) * 2;
    int ox0 = tx * 32 + 4 * hxp;
#pragma unroll
    for (int ch = 0; ch < 4; ++ch) {
        int cc = c0 + wid * 4 + ch;
        float* rb = out + ((size_t)(b * NC + cc) * 128 + oy0) * 128 + ox0;
        *reinterpret_cast<float4*>(rb)       = make_float4(r0[ch][0], r0[ch][1], r1[ch][0], r1[ch][1]);
        *reinterpret_cast<float4*>(rb + 128) = make_float4(r0[ch][2], r0[ch][3], r1[ch][2], r1[ch][3]);
    }
}

extern "C" void kernel_launch(void* const* d_in, const int* in_sizes, int n_in,
                              void* d_out, int out_size, void* d_ws, size_t ws_size,
                              hipStream_t stream) {
    const float* x     = (const float*)d_in[0];
    const float* w_enc = (const float*)d_in[1];
    const float* b_enc = (const float*)d_in[2];
    const float* w_kp  = (const float*)d_in[3];
    const float* b_kp  = (const float*)d_in[4];
    float* out = (float*)d_out;

    float* wt = (float*)d_ws;                    // 16384 f32
    unsigned* whr  = (unsigned*)(wt + 16384);    // 32256 u32
    unsigned* xch  = whr + 32256;                // 2*32*4096 = 262144 u32
    unsigned* kerh = xch + 262144;               // 2*32*2*3840 = 491520 u32

    prep_weights<<<190, 256, 0, stream>>>(w_kp, w_enc, whr, wt);
    encoder_kernel<<<256, 512, 0, stream>>>(x, wt, b_enc, xch);
    kp_conv_kernel<<<512, 256, 0, stream>>>(xch, whr, b_kp, kerh);
    gather_kernel<<<1024, 256, 0, stream>>>(x, kerh, out);
}